// Round 6
// baseline (569.806 us; speedup 1.0000x reference)
//
#include <hip/hip_runtime.h>
#include <math.h>

#define B_ 128
#define T_ 256
#define N_ 16
#define K_ 10
#define H_ 20
#define TN_ 4096     // T_*N_
#define NC_ 128      // t-pairs (chunks) per k

#define REP20(F) F(0) F(1) F(2) F(3) F(4) F(5) F(6) F(7) F(8) F(9) \
                 F(10) F(11) F(12) F(13) F(14) F(15) F(16) F(17) F(18) F(19)

__device__ __forceinline__ float wsum(float v)
{
#pragma unroll
    for (int off = 32; off; off >>= 1) v += __shfl_xor(v, off);
    return v;
}

// ---------------------------------------------------------------------------
// ONE fused kernel. Block = (kn = k*16+n, chunk = t-pair). 256 thr = 4 waves.
// Thread -> (tt = chunk*2 + tid/128, b = tid%128). One sample per thread,
// straight-line MLP (the only shape that hit ~95us), weights staged in LDS
// and read as BROADCAST float4 ds_reads (uniform addr -> conflict-free, and
// the values land in ArchVGPRs -- sidesteps the AGPR-spill bloat seen when
// weights stream via the scalar/flat paths: VGPR_Count=24 w/ 40 live floats).
//   - x standardized over b in-block (ddof=1, no eps), cross-wave via LDS
//   - t standardized over b (ddof=1, std+1e-8), z -> ws zbuf (coalesced)
//   - ticket per (k,chunk): 16th n-block computes products; penalty = pj^2
//     (product of 16 marginal means underflows to 0 in fp32 ref; R2-R5 pass)
//   - done-counter: last of 1280 winners writes out
// ---------------------------------------------------------------------------
__global__ __launch_bounds__(256, 4) void k_fused(
    const float* __restrict__ x,
    const float* __restrict__ W1, const float* __restrict__ b1,
    const float* __restrict__ W2, const float* __restrict__ b2,
    const float* __restrict__ W3, const float* __restrict__ b3,
    float* __restrict__ out,
    unsigned int* __restrict__ tickets,   // ws: 1280 u32, zeroed
    unsigned int* __restrict__ done,      // ws: 1 u32, zeroed
    float* __restrict__ acc,              // ws: 1 f32, zeroed
    float* __restrict__ zbuf)             // ws: [K][T][N][B] f32
{
    __shared__ __align__(16) float sw2[400];
    __shared__ __align__(16) float sw1[20], sb1[20], sb2[20], sw3[20];
    __shared__ float sb3s;
    __shared__ float red[4], red2[4];
    __shared__ int   flag;

    const int chunk = blockIdx.x;        // 0..127
    const int kn    = blockIdx.y;        // 0..159
    const int k     = kn >> 4;
    const int n     = kn & 15;
    const int tid   = threadIdx.x;
    const int wv    = tid >> 6;
    const int l     = tid & 63;
    const int half  = tid >> 7;          // which t of the pair
    const int hb    = half * 2;          // red[] base for this column
    const int tt    = chunk * 2 + half;  // global t
    const int b     = tid & 127;

    // ---- stage weights into LDS (coalesced) ----
    for (int j = tid; j < 400; j += 256) sw2[j] = W2[kn * 400 + j];
    if (tid < 20) {
        sw1[tid] = W1[kn * 20 + tid];
        sb1[tid] = b1[kn * 20 + tid];
        sb2[tid] = b2[kn * 20 + tid];
        sw3[tid] = W3[kn * 20 + tid];
    }
    if (tid == 32) sb3s = b3[kn];

    // ---- load x (scattered gather, L2-cached) + standardize over b ----
    const float xv = x[b * TN_ + tt * N_ + n];
    {
        const float s = wsum(xv);
        if (l == 0) red[wv] = s;
    }
    __syncthreads();                                    // also covers staging
    const float xmu = (red[hb] + red[hb + 1]) * (1.f / 128.f);
    const float xd  = xv - xmu;
    {
        const float s = wsum(xd * xd);
        if (l == 0) red2[wv] = s;
    }
    __syncthreads();
    const float u = xd * __builtin_amdgcn_rsqf((red2[hb] + red2[hb + 1]) * (1.f / 127.f));

    const float4* __restrict__ w1v = reinterpret_cast<const float4*>(sw1);
    const float4* __restrict__ b1v = reinterpret_cast<const float4*>(sb1);
    const float4* __restrict__ w2v = reinterpret_cast<const float4*>(sw2);
    const float4* __restrict__ w3v = reinterpret_cast<const float4*>(sw3);

    // ---- Layer 1 + ReLU ----
#define DECLH(i) float h##i;
    REP20(DECLH)
    float s1 = 0.f;
#define L1C(c,i0,i1,i2,i3) { const float4 w = w1v[c], bb = b1v[c]; \
    h##i0 = fmaxf(fmaf(u, w.x, bb.x), 0.f); s1 += h##i0; \
    h##i1 = fmaxf(fmaf(u, w.y, bb.y), 0.f); s1 += h##i1; \
    h##i2 = fmaxf(fmaf(u, w.z, bb.z), 0.f); s1 += h##i2; \
    h##i3 = fmaxf(fmaf(u, w.w, bb.w), 0.f); s1 += h##i3; }
    L1C(0,0,1,2,3) L1C(1,4,5,6,7) L1C(2,8,9,10,11) L1C(3,12,13,14,15) L1C(4,16,17,18,19)

    // ---- LayerNorm 1 (biased var, eps 1e-5) ----
    const float mu1 = s1 * 0.05f;
    float v1 = 0.f;
#define VAR1(i) { const float d = h##i - mu1; v1 = fmaf(d, d, v1); }
    REP20(VAR1)
    const float r1 = __builtin_amdgcn_rsqf(v1 * 0.05f + 1e-5f);
    const float m1 = mu1 * r1;
#define NRM1(i) h##i = fmaf(h##i, r1, -m1);
    REP20(NRM1)

    // ---- Layer 2 (20x20) + ReLU, weights via broadcast ds_read_b128 ----
#define DECLG(i) float g##i;
    REP20(DECLG)
    float s2 = 0.f;
#define L2C(o,c,i0,i1,i2,i3) { const float4 w = w2v[(o) * 5 + (c)]; \
    acc2 = fmaf(h##i0, w.x, acc2); acc2 = fmaf(h##i1, w.y, acc2); \
    acc2 = fmaf(h##i2, w.z, acc2); acc2 = fmaf(h##i3, w.w, acc2); }
#define L2ROW(o) { float acc2 = sb2[o]; \
    L2C(o,0,0,1,2,3) L2C(o,1,4,5,6,7) L2C(o,2,8,9,10,11) \
    L2C(o,3,12,13,14,15) L2C(o,4,16,17,18,19) \
    g##o = fmaxf(acc2, 0.f); s2 += g##o; }
    REP20(L2ROW)

    // ---- LayerNorm 2 fused into layer-3 dot ----
    const float mu2 = s2 * 0.05f;
    float v2 = 0.f;
#define VAR2(i) { const float d = g##i - mu2; v2 = fmaf(d, d, v2); }
    REP20(VAR2)
    const float r2 = __builtin_amdgcn_rsqf(v2 * 0.05f + 1e-5f);
    const float m2 = mu2 * r2;

    float tv = sb3s;
#define L3C(c,i0,i1,i2,i3) { const float4 w = w3v[c]; \
    tv = fmaf(fmaf(g##i0, r2, -m2), w.x, tv); \
    tv = fmaf(fmaf(g##i1, r2, -m2), w.y, tv); \
    tv = fmaf(fmaf(g##i2, r2, -m2), w.z, tv); \
    tv = fmaf(fmaf(g##i3, r2, -m2), w.w, tv); }
    L3C(0,0,1,2,3) L3C(1,4,5,6,7) L3C(2,8,9,10,11) L3C(3,12,13,14,15) L3C(4,16,17,18,19)

    // ---- standardize t over b (ddof=1, std+1e-8) ----
    __syncthreads();                     // protect red[] reuse
    {
        const float s = wsum(tv);
        if (l == 0) red[wv] = s;
    }
    __syncthreads();
    const float tmu = (red[hb] + red[hb + 1]) * (1.f / 128.f);
    const float e   = tv - tmu;
    {
        const float s = wsum(e * e);
        if (l == 0) red2[wv] = s;
    }
    __syncthreads();
    const float sd = sqrtf((red2[hb] + red2[hb + 1]) * (1.f / 127.f));
    const float z  = e * (1.f / (sd + 1e-8f));

    zbuf[(((size_t)k * T_ + tt) * N_ + n) * B_ + b] = z;

    // ---- ticket: last of the 16 n-blocks for (k,chunk) does products ----
    __syncthreads();                     // drains vmcnt -> z stores issued
    if (tid == 0) {
        __threadfence();                 // release
        flag = (atomicAdd(&tickets[k * NC_ + chunk], 1u) == 15u);
    }
    __syncthreads();
    if (!flag) return;
    if (tid == 0) __threadfence();       // acquire
    __syncthreads();

    // ---- P3: product over n per (tt,b); penalty = pj^2 ----
    const float* __restrict__ zr = zbuf + ((size_t)k * T_ + tt) * (N_ * B_);
    float p = zr[b];
#pragma unroll
    for (int nn = 1; nn < N_; ++nn) p *= zr[nn * B_ + b];
    {
        const float s = wsum(p);
        if (l == 0) red[wv] = s;
    }
    __syncthreads();
    if ((tid & 127) == 0) {
        const float pj = (red[hb] + red[hb + 1]) * (1.f / 128.f);
        atomicAdd(acc, pj * pj * (1.f / (K_ * T_)));
    }
    __syncthreads();
    if (tid == 0) {
        __threadfence();
        if (atomicAdd(done, 1u) == (K_ * NC_ - 1u))
            out[0] = atomicAdd(acc, 0.f);
    }
}

// ---------------------------------------------------------------------------
extern "C" void kernel_launch(void* const* d_in, const int* in_sizes, int n_in,
                              void* d_out, int out_size, void* d_ws, size_t ws_size,
                              hipStream_t stream)
{
    const float* x  = (const float*)d_in[0];
    const float* W1 = (const float*)d_in[1];
    const float* b1 = (const float*)d_in[2];
    const float* W2 = (const float*)d_in[3];
    const float* b2 = (const float*)d_in[4];
    const float* W3 = (const float*)d_in[5];
    const float* b3 = (const float*)d_in[6];
    float* out = (float*)d_out;

    char* ws = (char*)d_ws;
    unsigned int* tickets = (unsigned int*)ws;            // 1280 u32 (5120 B)
    unsigned int* done    = (unsigned int*)(ws + 6144);   // 1 u32
    float*        acc     = (float*)(ws + 6400);          // 1 f32
    float*        zbuf    = (float*)(ws + 8192);          // 20 MB [K][T][N][B]

    hipMemsetAsync(ws, 0, 8192, stream);

    dim3 grid(NC_, K_ * N_);                              // 128 x 160
    k_fused<<<grid, 256, 0, stream>>>(x, W1, b1, W2, b2, W3, b3,
                                      out, tickets, done, acc, zbuf);
}